// Round 1
// baseline (8147.600 us; speedup 1.0000x reference)
//
#include <hip/hip_runtime.h>

// Fused 2-layer LSTM (B=4096, T=512, I=H=32) + projection to 16.
// Decomposition: wave = 4 batch x 16 subs; sub owns 2 hidden units (8 gate rows/layer).
// WG = 4 waves = 16 batch; grid = 256 = 1 WG/CU. All h-sharing is intra-wave -> no
// barriers in the main loop (compiler-ordered LDS deps within the wave's lockstep stream).
// Weights staged in LDS fp32, pitch 68 floats (16B-aligned rows, bank spread).

namespace {
constexpr int TSTEPS = 512;
constexpr int HID    = 32;
constexpr int G4     = 128;           // 4*H gate rows
constexpr int CT     = 16;            // x staging chunk (timesteps)
constexpr int WPITCH = 68;            // weight row pitch (floats): [0..31]=W_ih row, [32..63]=W_hh row
constexpr int HPITCH = 36;            // h-vector pitch per batch
constexpr int XPITCH = CT * HID + 4;  // 516

__device__ __forceinline__ float sigmoidf_(float x) {
    return __fdividef(1.0f, 1.0f + __expf(-x));
}
__device__ __forceinline__ float tanhf_(float x) {
    // tanh(x) = 1 - 2/(1+e^{2x}); saturates correctly at +-inf
    return 1.0f - 2.0f * __fdividef(1.0f, 1.0f + __expf(2.0f * x));
}

__device__ __forceinline__ void ld32(const float* __restrict__ s, float v[32]) {
#pragma unroll
    for (int i = 0; i < 8; ++i) {
        float4 t = *(const float4*)&s[i * 4];
        v[4 * i + 0] = t.x; v[4 * i + 1] = t.y; v[4 * i + 2] = t.z; v[4 * i + 3] = t.w;
    }
}

__device__ __forceinline__ void dot8(const float* __restrict__ w, const float iv[32], float& a) {
#pragma unroll
    for (int i = 0; i < 8; ++i) {
        float4 wv = *(const float4*)&w[i * 4];
        a += wv.x * iv[4 * i + 0] + wv.y * iv[4 * i + 1] + wv.z * iv[4 * i + 2] + wv.w * iv[4 * i + 3];
    }
}

// One LSTM cell step for this thread's 2 hidden units.
__device__ __forceinline__ void cell(const float* __restrict__ W,  // LDS [128][WPITCH]
                                     const float bias[8],
                                     const float xv[32], const float hv[32],
                                     int sub, float& ca, float& cb,
                                     float& ho0, float& ho1) {
    float acc[8];
#pragma unroll
    for (int e = 0; e < 8; ++e) {
        const int row = (e >> 1) * 32 + sub * 2 + (e & 1);  // q = e>>1 in (i,f,g,o)
        float a = bias[e];
        dot8(&W[row * WPITCH], xv, a);        // input contribution
        dot8(&W[row * WPITCH + 32], hv, a);   // recurrent contribution
        acc[e] = a;
    }
    const float I0 = sigmoidf_(acc[0]), I1 = sigmoidf_(acc[1]);
    const float F0 = sigmoidf_(acc[2]), F1 = sigmoidf_(acc[3]);
    const float G0 = tanhf_(acc[4]),    G1 = tanhf_(acc[5]);
    const float O0 = sigmoidf_(acc[6]), O1 = sigmoidf_(acc[7]);
    ca = F0 * ca + I0 * G0;
    cb = F1 * cb + I1 * G1;
    ho0 = O0 * tanhf_(ca);
    ho1 = O1 * tanhf_(cb);
}
}  // namespace

__global__ __launch_bounds__(256, 1)
void lstm2_fused(const float* __restrict__ x,
                 const float* __restrict__ Wih1, const float* __restrict__ Whh1,
                 const float* __restrict__ bih1, const float* __restrict__ bhh1,
                 const float* __restrict__ Wih2, const float* __restrict__ Whh2,
                 const float* __restrict__ bih2, const float* __restrict__ bhh2,
                 const float* __restrict__ Wproj, const float* __restrict__ bproj,
                 float* __restrict__ out)
{
    __shared__ float W1[G4 * WPITCH];    // 34.0 KB
    __shared__ float W2[G4 * WPITCH];    // 34.0 KB
    __shared__ float XS[16 * XPITCH];    // 32.25 KB
    __shared__ float H1s[16 * HPITCH];   // 2.25 KB
    __shared__ float H2s[16 * HPITCH];   // 2.25 KB
    __shared__ float WPs[16 * HPITCH];   // 2.25 KB   -> ~107 KB total (1 WG/CU)

    const int tid = threadIdx.x;

    // Stage weights (coalesced global, stride-1 LDS writes)
    for (int idx = tid; idx < G4 * 32; idx += 256) {
        const int r = idx >> 5, c = idx & 31;
        W1[r * WPITCH + c]      = Wih1[idx];
        W1[r * WPITCH + 32 + c] = Whh1[idx];
        W2[r * WPITCH + c]      = Wih2[idx];
        W2[r * WPITCH + 32 + c] = Whh2[idx];
    }
    for (int idx = tid; idx < 16 * 32; idx += 256) {
        const int r = idx >> 5, c = idx & 31;
        WPs[r * HPITCH + c] = Wproj[idx];
    }
    __syncthreads();  // only barrier in the kernel

    const int wave = tid >> 6;
    const int lane = tid & 63;
    const int bw   = wave * 4 + (lane & 3);  // batch-in-WG [0,16): all 16 subs of a batch in ONE wave
    const int sub  = lane >> 2;              // [0,16): owns hidden units {2*sub, 2*sub+1}
    const int b    = blockIdx.x * 16 + bw;   // global batch

    float bias1[8], bias2[8];
#pragma unroll
    for (int e = 0; e < 8; ++e) {
        const int r = (e >> 1) * 32 + sub * 2 + (e & 1);
        bias1[e] = bih1[r] + bhh1[r];
        bias2[e] = bih2[r] + bhh2[r];
    }

    float c1a = 0.f, c1b = 0.f, c2a = 0.f, c2b = 0.f;
    *(float2*)&H1s[bw * HPITCH + sub * 2] = make_float2(0.f, 0.f);
    *(float2*)&H2s[bw * HPITCH + sub * 2] = make_float2(0.f, 0.f);
    // no barrier needed: producers/consumers of H1s/H2s/XS rows are the same wave

#pragma unroll 1
    for (int t0 = 0; t0 < TSTEPS; t0 += CT) {
        // Stage x[b, t0..t0+CT, :] for this wave's 4 batches (512 float4 per wave)
#pragma unroll
        for (int it = 0; it < 8; ++it) {
            const int idx4 = it * 64 + lane;
            const int bw4  = idx4 >> 7;     // 0..3
            const int r    = idx4 & 127;    // float4 index within batch chunk
            const int bb   = wave * 4 + bw4;
            const float4 v = *(const float4*)(x + (size_t)(blockIdx.x * 16 + bb) * (TSTEPS * HID)
                                                + t0 * HID + r * 4);
            *(float4*)&XS[bb * XPITCH + r * 4] = v;
        }

#pragma unroll 1
        for (int tt = 0; tt < CT; ++tt) {
            float xv[32], hv[32];
            // ---- layer 1 ----
            ld32(&XS[bw * XPITCH + tt * HID], xv);
            ld32(&H1s[bw * HPITCH], hv);
            float h10, h11;
            cell(W1, bias1, xv, hv, sub, c1a, c1b, h10, h11);
            *(float2*)&H1s[bw * HPITCH + sub * 2] = make_float2(h10, h11);
            // ---- layer 2 (input = new h1) ----
            ld32(&H1s[bw * HPITCH], xv);
            ld32(&H2s[bw * HPITCH], hv);
            float h20, h21;
            cell(W2, bias2, xv, hv, sub, c2a, c2b, h20, h21);
            *(float2*)&H2s[bw * HPITCH + sub * 2] = make_float2(h20, h21);
        }
    }

    // Projection: out[b][m] for m = sub (0..15)
    float a = bproj[sub];
#pragma unroll
    for (int i = 0; i < 8; ++i) {
        const float4 hvv = *(const float4*)&H2s[bw * HPITCH + i * 4];
        const float4 wv  = *(const float4*)&WPs[sub * HPITCH + i * 4];
        a += wv.x * hvv.x + wv.y * hvv.y + wv.z * hvv.z + wv.w * hvv.w;
    }
    out[b * 16 + sub] = a;
}

extern "C" void kernel_launch(void* const* d_in, const int* in_sizes, int n_in,
                              void* d_out, int out_size, void* d_ws, size_t ws_size,
                              hipStream_t stream) {
    const float* x     = (const float*)d_in[0];
    const float* Wih1  = (const float*)d_in[1];
    const float* Whh1  = (const float*)d_in[2];
    const float* bih1  = (const float*)d_in[3];
    const float* bhh1  = (const float*)d_in[4];
    const float* Wih2  = (const float*)d_in[5];
    const float* Whh2  = (const float*)d_in[6];
    const float* bih2  = (const float*)d_in[7];
    const float* bhh2  = (const float*)d_in[8];
    const float* Wproj = (const float*)d_in[9];
    const float* bproj = (const float*)d_in[10];
    float* out = (float*)d_out;

    dim3 grid(256), block(256);
    lstm2_fused<<<grid, block, 0, stream>>>(x, Wih1, Whh1, bih1, bhh1,
                                            Wih2, Whh2, bih2, bhh2,
                                            Wproj, bproj, out);
}

// Round 2
// 579.972 us; speedup vs baseline: 14.0483x; 14.0483x over previous
//
#include <hip/hip_runtime.h>

// Fused 2-layer LSTM (B=4096, T=512, I=H=32) + projection, via bf16 split-precision MFMA.
//
// Grid 256 WGs x 256 threads; WG owns 16 batches for the whole sequence (1 WG/CU).
// Per step: gates[16b,128rows] = A[16,64] x B[64,128] with A = (x_t || h) and weights
// unit-major-reordered. Each value is split fp32 -> bf16 hi + bf16 lo; 3-term MFMA
// (hi*hi + hi*lo + lo*hi) gives ~2^-18 relative error (fp32-quality).
//
// Wave w owns gate rows for units 8w..8w+7 (all 4 gates, unit-major reorder), all 16
// batches. Weights = persistent register B-fragments (64 VGPR/lane, both layers).
// A/B fragments are packed with the SAME (lane-group,elem)->k arrangement, so the exact
// HW K-mapping cancels in the dot product. C/D layout (HW-verified): col=lane&15 (gate
// row), row=(lane>>4)*4+reg (batch).
//
// i,f,g,o for a unit live in lanes l and l^8 -> one DPP row_ror:8 exchange.
// h stored in LDS as bf16 hi/lo planes, ping-pong (parity = tt&1); ONE barrier per step
// + one per 16-step chunk (x staging). x prefetched to registers one chunk ahead.

typedef __attribute__((ext_vector_type(4))) float f32x4;
typedef __attribute__((ext_vector_type(8))) short s16x8;

#define MFMA_B16(a, b, c) __builtin_amdgcn_mfma_f32_16x16x32_bf16(a, b, c, 0, 0, 0)

namespace {
constexpr int TSTEPS = 512;
constexpr int CT     = 16;   // timesteps per x-staging chunk

__device__ __forceinline__ ushort bf16rn(float x) {
    uint u = __float_as_uint(x);
    return (ushort)((u + 0x7FFFu + ((u >> 16) & 1u)) >> 16);
}
__device__ __forceinline__ float fromhi(ushort h) { return __uint_as_float(((uint)h) << 16); }

__device__ __forceinline__ void split8(const float v[8], s16x8& hi, s16x8& lo) {
#pragma unroll
    for (int e = 0; e < 8; ++e) {
        ushort hb = bf16rn(v[e]);
        hi[e] = (short)hb;
        lo[e] = (short)bf16rn(v[e] - fromhi(hb));
    }
}

// lane <- lane^8 exchange (row_ror:8 within 16-lane rows == xor 8)
__device__ __forceinline__ float xor8(float v) {
    return __int_as_float(__builtin_amdgcn_mov_dpp(__float_as_int(v), 0x128, 0xf, 0xf, true));
}

__device__ __forceinline__ float sigm(float x) {
    return __fdividef(1.0f, 1.0f + __expf(-x));
}

// One LSTM layer step for this lane. A-frags: a0* = K 0..31 (input), a1* = K 32..63 (own h).
// Wh/Wl: [n-tile][kt] register B-frags. Updates c[2], returns h[2] (batches bloc, bloc+1).
__device__ __forceinline__ void lstm_cell(
    const s16x8 a0h, const s16x8 a0l, const s16x8 a1h, const s16x8 a1l,
    const s16x8 (&Wh)[2][2], const s16x8 (&Wl)[2][2],
    const float b0, const float b1,
    const float kE, const float mm, const float aa, const int qh,
    float (&c)[2], float (&h)[2])
{
    f32x4 acc0 = {b0, b0, b0, b0};
    f32x4 acc1 = {b1, b1, b1, b1};
    acc0 = MFMA_B16(a0h, Wh[0][0], acc0);
    acc0 = MFMA_B16(a0h, Wl[0][0], acc0);
    acc0 = MFMA_B16(a0l, Wh[0][0], acc0);
    acc0 = MFMA_B16(a1h, Wh[0][1], acc0);
    acc0 = MFMA_B16(a1h, Wl[0][1], acc0);
    acc0 = MFMA_B16(a1l, Wh[0][1], acc0);
    acc1 = MFMA_B16(a0h, Wh[1][0], acc1);
    acc1 = MFMA_B16(a0h, Wl[1][0], acc1);
    acc1 = MFMA_B16(a0l, Wh[1][0], acc1);
    acc1 = MFMA_B16(a1h, Wh[1][1], acc1);
    acc1 = MFMA_B16(a1h, Wl[1][1], acc1);
    acc1 = MFMA_B16(a1l, Wh[1][1], acc1);

    // acc0: rows i (lanes qh=0) / f (qh=1): all sigmoid.
    // acc1: rows g (qh=0, tanh) / o (qh=1, sigmoid): uniform code via lane consts.
    f32x4 s0, s1;
#pragma unroll
    for (int r = 0; r < 4; ++r) {
        s0[r] = sigm(acc0[r]);
        float t = __fdividef(1.0f, 1.0f + __expf(-kE * acc1[r]));
        s1[r] = fmaf(t, mm, aa);
    }
    f32x4 r0, r1;
#pragma unroll
    for (int r = 0; r < 4; ++r) { r0[r] = xor8(s0[r]); r1[r] = xor8(s1[r]); }
    // lane handles batches (lane>>4)*4 + qh*2 + j, j=0,1 (regs qh*2+j)
#pragma unroll
    for (int j = 0; j < 2; ++j) {
        float iv = qh ? r0[2 + j] : s0[j];
        float fv = qh ? s0[2 + j] : r0[j];
        float gv = qh ? r1[2 + j] : s1[j];
        float ov = qh ? s1[2 + j] : r1[j];
        float cc = fmaf(fv, c[j], iv * gv);
        c[j] = cc;
        float t = __fdividef(1.0f, 1.0f + __expf(-2.0f * cc));
        h[j] = ov * fmaf(2.0f, t, -1.0f);
    }
}
}  // namespace

__global__ __launch_bounds__(256, 1)
void lstm2_mfma(const float* __restrict__ x,
                const float* __restrict__ Wih1, const float* __restrict__ Whh1,
                const float* __restrict__ bih1, const float* __restrict__ bhh1,
                const float* __restrict__ Wih2, const float* __restrict__ Whh2,
                const float* __restrict__ bih2, const float* __restrict__ bhh2,
                const float* __restrict__ Wproj, const float* __restrict__ bproj,
                float* __restrict__ out)
{
    // frag-unit LDS: index = ((t_or_pp*2 + plane)*4 + kgroup)*16 + b ; 16B per frag
    __shared__ s16x8 XA[CT * 2 * 4 * 16];   // 32 KB: x chunk, split bf16
    __shared__ s16x8 H1[2 * 2 * 4 * 16];    // 4 KB: [pp][plane][kg][b]
    __shared__ s16x8 H2[2 * 2 * 4 * 16];    // 4 KB
    __shared__ float HF[16 * 33];           // final h2, fp32
    __shared__ float WPs[16 * 33];          // W_proj
    __shared__ float BPs[16];

    const int tid = threadIdx.x;
    const int w   = tid >> 6;        // wave: owns units 8w..8w+7
    const int l   = tid & 63;
    const int col = l & 15;          // A: batch row; B/D: gate-row-in-tile
    const int g   = l >> 4;          // k-group (and D batch group)
    const int qh  = (l >> 3) & 1;
    const int ul  = l & 7;           // unit-local

    // ---- persistent register B-fragments (weights, unit-major row reorder) ----
    // wave-local gate row' = tile*16 + (col>>3)*8... mapped: q = n*2 + (col>>3),
    // unit = w*8 + (col&7)  ->  original row R = q*32 + unit.
    s16x8 Bh[2][2][2], Bl[2][2][2];  // [layer][n-tile][kt]
    float bias[2][2];
    {
        const float* WI[2]  = {Wih1, Wih2};
        const float* WH[2]  = {Whh1, Whh2};
        const float* BIa[2] = {bih1, bih2};
        const float* BHa[2] = {bhh1, bhh2};
#pragma unroll
        for (int L = 0; L < 2; ++L) {
#pragma unroll
            for (int n = 0; n < 2; ++n) {
                const int R = (n * 2 + (col >> 3)) * 32 + w * 8 + (col & 7);
                bias[L][n] = BIa[L][R] + BHa[L][R];
#pragma unroll
                for (int kt = 0; kt < 2; ++kt) {
                    const float* src = (kt ? WH[L] : WI[L]) + R * 32 + g * 8;
                    float v[8];
#pragma unroll
                    for (int e = 0; e < 8; ++e) v[e] = src[e];
                    split8(v, Bh[L][n][kt], Bl[L][n][kt]);
                }
            }
        }
    }

    // lane constants for tile-1 activations (g: tanh, o: sigmoid)
    const float kE = qh ? 1.0f : 2.0f;
    const float mm = qh ? 1.0f : 2.0f;
    const float aa = qh ? 0.0f : -1.0f;

    for (int i = tid; i < 16 * 32; i += 256) WPs[(i >> 5) * 33 + (i & 31)] = Wproj[i];
    if (tid < 16) BPs[tid] = bproj[tid];
    {
        ushort* z1 = (ushort*)H1;
        ushort* z2 = (ushort*)H2;
        for (int i = tid; i < 2 * 2 * 4 * 16 * 8; i += 256) { z1[i] = 0; z2[i] = 0; }
    }

    float c1[2] = {0.f, 0.f}, c2[2] = {0.f, 0.f};
    const int bloc = g * 4 + qh * 2;             // first of this lane's 2 batches
    const size_t bglob = (size_t)blockIdx.x * 16;

    // x staging: thread -> (batch stb, timestep stt) within chunk; b-slot XOR by t-parity
    const int stb = tid >> 4;
    const int stt = tid & 15;
    const int bsw = stb ^ ((stt & 1) << 2);
    const float* xsrc = x + (bglob + stb) * (size_t)(TSTEPS * 32) + stt * 32;

    float4 xv[8];
#pragma unroll
    for (int i = 0; i < 8; ++i) xv[i] = ((const float4*)xsrc)[i];

    for (int t0 = 0; t0 < TSTEPS; t0 += CT) {
        // write prefetched chunk to XA (split bf16), then issue next chunk's loads
#pragma unroll
        for (int kg = 0; kg < 4; ++kg) {
            float v[8];
            float4 va = xv[kg * 2], vb = xv[kg * 2 + 1];
            v[0] = va.x; v[1] = va.y; v[2] = va.z; v[3] = va.w;
            v[4] = vb.x; v[5] = vb.y; v[6] = vb.z; v[7] = vb.w;
            s16x8 hi, lo;
            split8(v, hi, lo);
            XA[((stt * 2 + 0) * 4 + kg) * 16 + bsw] = hi;
            XA[((stt * 2 + 1) * 4 + kg) * 16 + bsw] = lo;
        }
        if (t0 + CT < TSTEPS) {
            const float* p = xsrc + (t0 + CT) * 32;
#pragma unroll
            for (int i = 0; i < 8; ++i) xv[i] = ((const float4*)p)[i];
        }
        __syncthreads();

#pragma unroll 2
        for (int tt = 0; tt < CT; ++tt) {
            const int pp  = tt & 1;                   // h ping-pong parity
            const int bxa = col ^ ((tt & 1) << 2);    // XA de-swizzle
            // ---- layer 1: A = (x_t || h1[pp]) ----
            s16x8 a0h = XA[((tt * 2 + 0) * 4 + g) * 16 + bxa];
            s16x8 a0l = XA[((tt * 2 + 1) * 4 + g) * 16 + bxa];
            s16x8 a1h = H1[((pp * 2 + 0) * 4 + g) * 16 + col];
            s16x8 a1l = H1[((pp * 2 + 1) * 4 + g) * 16 + col];
            float h1v[2];
            lstm_cell(a0h, a0l, a1h, a1l, Bh[0], Bl[0], bias[0][0], bias[0][1],
                      kE, mm, aa, qh, c1, h1v);
            {   // write h1 -> H1[pp^1]
                ushort* d = (ushort*)H1;
                const int basehi = (((pp ^ 1) * 2 + 0) * 4 + w) * 128;
                const int baselo = (((pp ^ 1) * 2 + 1) * 4 + w) * 128;
#pragma unroll
                for (int j = 0; j < 2; ++j) {
                    ushort hb = bf16rn(h1v[j]);
                    ushort lb = bf16rn(h1v[j] - fromhi(hb));
                    d[basehi + (bloc + j) * 8 + ul] = hb;
                    d[baselo + (bloc + j) * 8 + ul] = lb;
                }
            }
            __syncthreads();   // the ONE barrier per step
            // ---- layer 2: A = (h1[pp^1] || h2[pp]) ----
            s16x8 e0h = H1[(((pp ^ 1) * 2 + 0) * 4 + g) * 16 + col];
            s16x8 e0l = H1[(((pp ^ 1) * 2 + 1) * 4 + g) * 16 + col];
            s16x8 e1h = H2[((pp * 2 + 0) * 4 + g) * 16 + col];
            s16x8 e1l = H2[((pp * 2 + 1) * 4 + g) * 16 + col];
            float h2v[2];
            lstm_cell(e0h, e0l, e1h, e1l, Bh[1], Bl[1], bias[1][0], bias[1][1],
                      kE, mm, aa, qh, c2, h2v);
            {   // write h2 -> H2[pp^1]
                ushort* d = (ushort*)H2;
                const int basehi = (((pp ^ 1) * 2 + 0) * 4 + w) * 128;
                const int baselo = (((pp ^ 1) * 2 + 1) * 4 + w) * 128;
#pragma unroll
                for (int j = 0; j < 2; ++j) {
                    ushort hb = bf16rn(h2v[j]);
                    ushort lb = bf16rn(h2v[j] - fromhi(hb));
                    d[basehi + (bloc + j) * 8 + ul] = hb;
                    d[baselo + (bloc + j) * 8 + ul] = lb;
                }
            }
            if (t0 + tt == TSTEPS - 1) {   // uniform branch: capture final h2 in fp32
#pragma unroll
                for (int j = 0; j < 2; ++j) HF[(bloc + j) * 33 + w * 8 + ul] = h2v[j];
            }
        }
    }

    __syncthreads();
    // ---- projection: lane -> (batch b = w*4+g, out-col m = col) ----
    {
        const int b = w * 4 + g;
        const int m = col;
        float a = BPs[m];
        const float* hp = &HF[b * 33];
        const float* wp = &WPs[m * 33];
#pragma unroll
        for (int k = 0; k < 32; ++k) a = fmaf(hp[k], wp[k], a);
        out[(bglob + b) * 16 + m] = a;
    }
}

extern "C" void kernel_launch(void* const* d_in, const int* in_sizes, int n_in,
                              void* d_out, int out_size, void* d_ws, size_t ws_size,
                              hipStream_t stream) {
    const float* x     = (const float*)d_in[0];
    const float* Wih1  = (const float*)d_in[1];
    const float* Whh1  = (const float*)d_in[2];
    const float* bih1  = (const float*)d_in[3];
    const float* bhh1  = (const float*)d_in[4];
    const float* Wih2  = (const float*)d_in[5];
    const float* Whh2  = (const float*)d_in[6];
    const float* bih2  = (const float*)d_in[7];
    const float* bhh2  = (const float*)d_in[8];
    const float* Wproj = (const float*)d_in[9];
    const float* bproj = (const float*)d_in[10];
    float* out = (float*)d_out;

    dim3 grid(256), block(256);
    lstm2_mfma<<<grid, block, 0, stream>>>(x, Wih1, Whh1, bih1, bhh1,
                                           Wih2, Whh2, bih2, bhh2,
                                           Wproj, bproj, out);
}

// Round 3
// 487.291 us; speedup vs baseline: 16.7202x; 1.1902x over previous
//
#include <hip/hip_runtime.h>

// Fused 2-layer LSTM (B=4096, T=512, I=H=32) + projection, bf16 split-precision MFMA.
// Round-3 restructure: WEIGHTS on M (A operand), BATCH on N (B operand).
// WG = 512 threads = 8 waves, 16 batches, grid 256 (1 WG/CU, 2 waves/SIMD).
// Wave wv owns units wv*4..wv*4+3 (16 reordered gate rows = 1 M-tile).
// D layout (row=(l>>4)*4+reg, col=l&15): lane's 4 regs = (i,f,g,o) of unit wv*4+(l>>4),
// batch l&15 -> cell update is fully lane-local (no cross-lane ops, no selects).
// Weights pre-scaled by -1 (i,f,o) / -2 (g) so sigmoid/tanh = exp+add+rcp.
// Split precision: val = bf16(hi) + bf16(lo); acc += Whi*(dhi+dlo) + Wlo*dhi (~2^-18 err).
// One barrier per step (proof in analysis: all cross-slot hazards are barrier-separated).

typedef __attribute__((ext_vector_type(4))) float f32x4;
typedef __attribute__((ext_vector_type(8))) short s16x8;

#define MFMA_B16(a, b, c) __builtin_amdgcn_mfma_f32_16x16x32_bf16(a, b, c, 0, 0, 0)

namespace {
constexpr int TSTEPS = 512;
constexpr int CT     = 16;   // timesteps per x-staging chunk
constexpr int PITCH  = 40;   // shorts per (plane,batch) row: 80 B, 16B-aligned, bank-spread

__device__ __forceinline__ ushort bf16rn(float x) {
    uint u = __float_as_uint(x);
    return (ushort)((u + 0x7FFFu + ((u >> 16) & 1u)) >> 16);
}
__device__ __forceinline__ float fromhi(ushort h) { return __uint_as_float(((uint)h) << 16); }

// acc = -k*z  ->  returns sigmoid(k*z) = 1/(1+e^acc)
__device__ __forceinline__ float sigm_pre(float acc) {
    return __fdividef(1.0f, 1.0f + __expf(acc));
}

// One LSTM cell step for this lane's (unit, batch). Weights Wh/Wl indexed [kt].
// Returns h; updates c. acc regs = (i,f,g,o) preactivations, pre-scaled by -1/-2.
__device__ __forceinline__ float cell2(
    const s16x8 b0h, const s16x8 b0l, const s16x8 b1h, const s16x8 b1l,
    const s16x8 (&Wh)[2], const s16x8 (&Wl)[2], const f32x4 bias, float& c)
{
    f32x4 acc = bias;
    acc = MFMA_B16(Wh[0], b0h, acc);
    acc = MFMA_B16(Wh[0], b0l, acc);
    acc = MFMA_B16(Wl[0], b0h, acc);
    acc = MFMA_B16(Wh[1], b1h, acc);
    acc = MFMA_B16(Wh[1], b1l, acc);
    acc = MFMA_B16(Wl[1], b1h, acc);
    const float iv = sigm_pre(acc[0]);
    const float fv = sigm_pre(acc[1]);
    const float gv = fmaf(2.0f, sigm_pre(acc[2]), -1.0f);  // tanh via sigma(2z)
    const float ov = sigm_pre(acc[3]);
    c = fmaf(fv, c, iv * gv);
    const float u = sigm_pre(-2.0f * c);                   // sigma(2c)
    return ov * fmaf(2.0f, u, -1.0f);                      // o * tanh(c)
}
}  // namespace

__global__ __launch_bounds__(512, 1)
void lstm2_mfma2(const float* __restrict__ x,
                 const float* __restrict__ Wih1, const float* __restrict__ Whh1,
                 const float* __restrict__ bih1, const float* __restrict__ bhh1,
                 const float* __restrict__ Wih2, const float* __restrict__ Whh2,
                 const float* __restrict__ bih2, const float* __restrict__ bhh2,
                 const float* __restrict__ Wproj, const float* __restrict__ bproj,
                 float* __restrict__ out)
{
    // layouts (shorts): XA[((tt*2+plane)*16 + batch)*PITCH + k]   k = x-dim 0..31
    //                   H*[((pp*2+plane)*16 + batch)*PITCH + k]   k = unit 0..31
    __shared__ __align__(16) ushort XA[CT * 2 * 16 * PITCH];  // 40 KB
    __shared__ __align__(16) ushort H1[2 * 2 * 16 * PITCH];   // 5 KB
    __shared__ __align__(16) ushort H2[2 * 2 * 16 * PITCH];   // 5 KB
    __shared__ float HF[16 * 33];
    __shared__ float WPs[16 * 33];
    __shared__ float BPs[16];

    const int tid  = threadIdx.x;
    const int wv   = tid >> 6;       // wave 0..7: owns units wv*4..wv*4+3
    const int l    = tid & 63;
    const int colB = l & 15;         // B-frag col = batch; also A-frag row for loading
    const int g    = l >> 4;         // k-group (B/A frag); also lane's local unit (D rows)

    // ---- persistent register A-fragments: weights, unit-major reorder, pre-scaled ----
    // A-frag: lane holds A[row = l&15, k = g*8+e]. Tile row r = lu*4+q -> unit wv*4+lu, gate q.
    s16x8 Whi[2][2], Wlo[2][2];   // [layer][kt: 0=input, 1=recurrent]
    f32x4 bias2[2];
    {
        const float* WI[2]  = {Wih1, Wih2};
        const float* WH[2]  = {Whh1, Whh2};
        const float* BIa[2] = {bih1, bih2};
        const float* BHa[2] = {bhh1, bhh2};
        const int rA = l & 15;
        const int qW = rA & 3;
        const int RW = qW * 32 + wv * 4 + (rA >> 2);
        const float sw = (qW == 2) ? -2.0f : -1.0f;
#pragma unroll
        for (int L = 0; L < 2; ++L) {
#pragma unroll
            for (int kt = 0; kt < 2; ++kt) {
                const float* src = (kt ? WH[L] : WI[L]) + RW * 32 + g * 8;
#pragma unroll
                for (int e = 0; e < 8; ++e) {
                    const float v = src[e] * sw;
                    const ushort hb = bf16rn(v);
                    Whi[L][kt][e] = (short)hb;
                    Wlo[L][kt][e] = (short)bf16rn(v - fromhi(hb));
                }
            }
            // bias for this lane's (unit = wv*4+g), regs q=0..3
            f32x4 bb;
#pragma unroll
            for (int q = 0; q < 4; ++q) {
                const int R = q * 32 + wv * 4 + g;
                bb[q] = ((q == 2) ? -2.0f : -1.0f) * (BIa[L][R] + BHa[L][R]);
            }
            bias2[L] = bb;
        }
    }

    for (int i = tid; i < 16 * 32; i += 512) WPs[(i >> 5) * 33 + (i & 31)] = Wproj[i];
    if (tid < 16) BPs[tid] = bproj[tid];
    for (int i = tid; i < 2 * 2 * 16 * PITCH; i += 512) { H1[i] = 0; H2[i] = 0; }

    const size_t bglob = (size_t)blockIdx.x * 16;

    // x staging map: sb = tid&15 (batch), st2 = tid>>5 (timestep), xhalf = (tid>>4)&1.
    // (Uncoalesced 16B global loads, prefetched a chunk ahead; keeps LDS writes bank-spread.)
    const int sb    = tid & 15;
    const int st2   = tid >> 5;
    const int xhalf = (tid >> 4) & 1;
    const float* xsrc = x + ((bglob + sb) * TSTEPS + st2) * 32 + xhalf * 16;

    float4 xv[4];
#pragma unroll
    for (int i = 0; i < 4; ++i) xv[i] = ((const float4*)xsrc)[i];

    float c1 = 0.f, c2 = 0.f, h2last = 0.f;
    const int unit = wv * 4 + g;     // this lane's unit for h-writes

    for (int t0 = 0; t0 < TSTEPS; t0 += CT) {
        // ---- write prefetched x chunk to XA as split bf16 ----
        {
            s16x8 ha, hb_, la, lb_;
#pragma unroll
            for (int k = 0; k < 4; ++k) {
                const float fv4[4] = {xv[k].x, xv[k].y, xv[k].z, xv[k].w};
#pragma unroll
                for (int j = 0; j < 4; ++j) {
                    const int idx = k * 4 + j;
                    const ushort hb = bf16rn(fv4[j]);
                    const ushort lb = bf16rn(fv4[j] - fromhi(hb));
                    if (idx < 8) { ha[idx] = (short)hb; la[idx] = (short)lb; }
                    else         { hb_[idx - 8] = (short)hb; lb_[idx - 8] = (short)lb; }
                }
            }
            const int bh = ((st2 * 2 + 0) * 16 + sb) * PITCH + xhalf * 16;
            const int bl = ((st2 * 2 + 1) * 16 + sb) * PITCH + xhalf * 16;
            *(s16x8*)&XA[bh]     = ha;
            *(s16x8*)&XA[bh + 8] = hb_;
            *(s16x8*)&XA[bl]     = la;
            *(s16x8*)&XA[bl + 8] = lb_;
        }
        if (t0 + CT < TSTEPS) {
            const float4* p = (const float4*)(xsrc + (size_t)(t0 + CT) * 32);
#pragma unroll
            for (int i = 0; i < 4; ++i) xv[i] = p[i];
        }
        __syncthreads();   // XA ready (also separates from last chunk's reads)

#pragma unroll 2
        for (int tt = 0; tt < CT; ++tt) {
            const int ts  = t0 + tt;
            const int pp  = ts & 1;
            const int ppn = pp ^ 1;
            // ---- layer 1: B = (x_t || h1[pp]) ----
            const s16x8 xh = *(const s16x8*)&XA[((tt * 2 + 0) * 16 + colB) * PITCH + g * 8];
            const s16x8 xl = *(const s16x8*)&XA[((tt * 2 + 1) * 16 + colB) * PITCH + g * 8];
            const s16x8 ah = *(const s16x8*)&H1[((pp * 2 + 0) * 16 + colB) * PITCH + g * 8];
            const s16x8 al = *(const s16x8*)&H1[((pp * 2 + 1) * 16 + colB) * PITCH + g * 8];
            const float h1v = cell2(xh, xl, ah, al, Whi[0], Wlo[0], bias2[0], c1);
            {
                const ushort hb = bf16rn(h1v);
                const ushort lb = bf16rn(h1v - fromhi(hb));
                H1[((ppn * 2 + 0) * 16 + colB) * PITCH + unit] = hb;
                H1[((ppn * 2 + 1) * 16 + colB) * PITCH + unit] = lb;
            }
            __syncthreads();   // the ONE barrier per step
            // ---- layer 2: B = (h1[ppn] || h2[pp]) ----
            const s16x8 eh = *(const s16x8*)&H1[((ppn * 2 + 0) * 16 + colB) * PITCH + g * 8];
            const s16x8 el = *(const s16x8*)&H1[((ppn * 2 + 1) * 16 + colB) * PITCH + g * 8];
            const s16x8 fh = *(const s16x8*)&H2[((pp * 2 + 0) * 16 + colB) * PITCH + g * 8];
            const s16x8 fl = *(const s16x8*)&H2[((pp * 2 + 1) * 16 + colB) * PITCH + g * 8];
            const float h2v = cell2(eh, el, fh, fl, Whi[1], Wlo[1], bias2[1], c2);
            {
                const ushort hb = bf16rn(h2v);
                const ushort lb = bf16rn(h2v - fromhi(hb));
                H2[((ppn * 2 + 0) * 16 + colB) * PITCH + unit] = hb;
                H2[((ppn * 2 + 1) * 16 + colB) * PITCH + unit] = lb;
            }
            h2last = h2v;
        }
    }

    // ---- epilogue: gather final h2 (fp32) and project ----
    HF[colB * 33 + unit] = h2last;
    __syncthreads();
    if (tid < 256) {
        const int b = tid >> 4, m = tid & 15;
        float a = BPs[m];
        const float* hp = &HF[b * 33];
        const float* wp = &WPs[m * 33];
#pragma unroll
        for (int k = 0; k < 32; ++k) a = fmaf(hp[k], wp[k], a);
        out[(bglob + b) * 16 + m] = a;
    }
}

extern "C" void kernel_launch(void* const* d_in, const int* in_sizes, int n_in,
                              void* d_out, int out_size, void* d_ws, size_t ws_size,
                              hipStream_t stream) {
    const float* x     = (const float*)d_in[0];
    const float* Wih1  = (const float*)d_in[1];
    const float* Whh1  = (const float*)d_in[2];
    const float* bih1  = (const float*)d_in[3];
    const float* bhh1  = (const float*)d_in[4];
    const float* Wih2  = (const float*)d_in[5];
    const float* Whh2  = (const float*)d_in[6];
    const float* bih2  = (const float*)d_in[7];
    const float* bhh2  = (const float*)d_in[8];
    const float* Wproj = (const float*)d_in[9];
    const float* bproj = (const float*)d_in[10];
    float* out = (float*)d_out;

    dim3 grid(256), block(512);
    lstm2_mfma2<<<grid, block, 0, stream>>>(x, Wih1, Whh1, bih1, bhh1,
                                            Wih2, Whh2, bih2, bhh2,
                                            Wproj, bproj, out);
}

// Round 4
// 285.661 us; speedup vs baseline: 28.5220x; 1.7058x over previous
//
#include <hip/hip_runtime.h>

// Fused 2-layer LSTM (B=4096, T=512, I=H=32) + projection — bf16 split-precision MFMA,
// LAYER-PIPELINED: waves 0-3 compute layer 1 at step t while waves 4-7 compute layer 2
// at step t-1. One barrier per step (was 2), serial chain per step = ONE cell (was 2).
//
// Each wave owns 32 gate rows (2 M-tiles of 16) of its layer; weights+bias persistent
// in registers, pre-scaled by -log2e (i,f,o) / -2log2e (g) so sigmoid = rcp(1+exp2(acc)).
// D layout (row=(l>>4)*4+reg, col=l&15=batch): lane's acc regs = (i,f,g,o) of units
// u0=wq*8+2g (tile 0) and u0+1 (tile 1) -> cell update lane-local; h-write = 2 packed
// b32 LDS writes. Split precision: W*d ~= Whi*(dhi+dlo) + Wlo*dhi (~2^-18 rel err).
//
// Pipeline hazards (1 barrier/iter suffices): at iter i, A reads H1[(i+1)&1], writes
// H1[i&1]; B reads H1[(i+1)&1] & H2[i&1], writes H2[(i+1)&1]. Same-iter buffers are
// disjoint; all cross-iter read/write pairs are separated by the end-of-iter barrier.
// Final h2[511] computed in an epilogue step (i=512) by group B.

typedef __attribute__((ext_vector_type(4))) float f32x4;
typedef __attribute__((ext_vector_type(8))) short s16x8;

#define MFMA_B16(a, b, c) __builtin_amdgcn_mfma_f32_16x16x32_bf16(a, b, c, 0, 0, 0)

namespace {
constexpr int TSTEPS = 512;
constexpr int CT     = 16;   // timesteps per x-staging chunk
constexpr int PITCH  = 40;   // shorts per (plane,batch) row: 80 B, 16B-aligned
constexpr float LOG2E = 1.4426950408889634f;

__device__ __forceinline__ ushort bf16rn(float x) {
    uint u = __float_as_uint(x);
    return (ushort)((u + 0x7FFFu + ((u >> 16) & 1u)) >> 16);
}
__device__ __forceinline__ float fromhi(ushort h) { return __uint_as_float(((uint)h) << 16); }

// acc = -log2e * z  ->  sigmoid(z) = rcp(1 + exp2(acc)); v_exp_f32 + v_add + v_rcp
__device__ __forceinline__ float sigm2(float a) {
    return __builtin_amdgcn_rcpf(1.0f + __builtin_amdgcn_exp2f(a));
}

struct LayerW {
    s16x8 Whi[2][2];   // [m-tile][kt: 0=input-K, 1=recurrent-K]
    s16x8 Wlo[2][2];
    f32x4 bias[2];     // [m-tile], regs = gates (i,f,g,o) of unit u0+m, pre-scaled
};

// Two M-tiles of one layer for this lane: units u0, u0+1. Updates c[2], returns h[2].
__device__ __forceinline__ void cell_pair(
    const s16x8 b0h, const s16x8 b0l, const s16x8 b1h, const s16x8 b1l,
    const LayerW& W, float (&c)[2], float (&h)[2])
{
    f32x4 a0 = W.bias[0], a1 = W.bias[1];
    a0 = MFMA_B16(W.Whi[0][0], b0h, a0);  a1 = MFMA_B16(W.Whi[1][0], b0h, a1);
    a0 = MFMA_B16(W.Whi[0][0], b0l, a0);  a1 = MFMA_B16(W.Whi[1][0], b0l, a1);
    a0 = MFMA_B16(W.Wlo[0][0], b0h, a0);  a1 = MFMA_B16(W.Wlo[1][0], b0h, a1);
    a0 = MFMA_B16(W.Whi[0][1], b1h, a0);  a1 = MFMA_B16(W.Whi[1][1], b1h, a1);
    a0 = MFMA_B16(W.Whi[0][1], b1l, a0);  a1 = MFMA_B16(W.Whi[1][1], b1l, a1);
    a0 = MFMA_B16(W.Wlo[0][1], b1h, a0);  a1 = MFMA_B16(W.Wlo[1][1], b1h, a1);
#pragma unroll
    for (int m = 0; m < 2; ++m) {
        const f32x4 acc = m ? a1 : a0;
        const float iv = sigm2(acc[0]);
        const float fv = sigm2(acc[1]);
        const float gv = fmaf(2.0f, sigm2(acc[2]), -1.0f);   // tanh(z) = 2*sigma(2z)-1
        const float ov = sigm2(acc[3]);
        const float cc = fmaf(fv, c[m], iv * gv);
        c[m] = cc;
        const float th = fmaf(2.0f, sigm2(cc * (-2.0f * LOG2E)), -1.0f);
        h[m] = ov * th;
    }
}
}  // namespace

__global__ __launch_bounds__(512, 1)
void lstm2_pipe(const float* __restrict__ x,
                const float* __restrict__ Wih1, const float* __restrict__ Whh1,
                const float* __restrict__ bih1, const float* __restrict__ bhh1,
                const float* __restrict__ Wih2, const float* __restrict__ Whh2,
                const float* __restrict__ bih2, const float* __restrict__ bhh2,
                const float* __restrict__ Wproj, const float* __restrict__ bproj,
                float* __restrict__ out)
{
    // shorts: XA[((tt*2+plane)*16 + batch)*PITCH + k]; H*[((buf*2+plane)*16 + batch)*PITCH + unit]
    __shared__ __align__(16) ushort XA[CT * 2 * 16 * PITCH];  // 40 KB
    __shared__ __align__(16) ushort H1[2 * 2 * 16 * PITCH];   // 5 KB
    __shared__ __align__(16) ushort H2[2 * 2 * 16 * PITCH];   // 5 KB
    __shared__ float HF[16 * 33];
    __shared__ float WPs[16 * 33];
    __shared__ float BPs[16];

    const int tid  = threadIdx.x;
    const int wv   = tid >> 6;       // wave
    const int L    = wv >> 2;        // 0: layer-1 group, 1: layer-2 group
    const int wq   = wv & 3;         // quarter within group: owns units wq*8..wq*8+7
    const int l    = tid & 63;
    const int colB = l & 15;         // batch (B-frag col / A-frag row / D col)
    const int g    = l >> 4;         // k-group; D row group

    // ---- persistent register weights for layer L (2 M-tiles), pre-scaled ----
    // tile m, A-row rA -> unit wq*8 + (rA>>2)*2 + m, gate rA&3 (lane's units adjacent)
    LayerW W;
    {
        const float* WI = L ? Wih2 : Wih1;
        const float* WH = L ? Whh2 : Whh1;
        const float* BI = L ? bih2 : bih1;
        const float* BH = L ? bhh2 : bhh1;
        const int q  = colB & 3;
        const int ut = (colB >> 2) * 2;
        const float sw = ((q == 2) ? -2.0f : -1.0f) * LOG2E;
#pragma unroll
        for (int m = 0; m < 2; ++m) {
            const int R = q * 32 + wq * 8 + ut + m;
#pragma unroll
            for (int kt = 0; kt < 2; ++kt) {
                const float* src = (kt ? WH : WI) + R * 32 + g * 8;
#pragma unroll
                for (int e = 0; e < 8; ++e) {
                    const float v = src[e] * sw;
                    const ushort hb = bf16rn(v);
                    W.Whi[m][kt][e] = (short)hb;
                    W.Wlo[m][kt][e] = (short)bf16rn(v - fromhi(hb));
                }
            }
            f32x4 bb;
#pragma unroll
            for (int qq = 0; qq < 4; ++qq) {
                const int Rb = qq * 32 + wq * 8 + 2 * g + m;
                bb[qq] = (((qq == 2) ? -2.0f : -1.0f) * LOG2E) * (BI[Rb] + BH[Rb]);
            }
            W.bias[m] = bb;
        }
    }

    for (int i = tid; i < 16 * 32; i += 512) WPs[(i >> 5) * 33 + (i & 31)] = Wproj[i];
    if (tid < 16) BPs[tid] = bproj[tid];
    for (int i = tid; i < 2 * 2 * 16 * PITCH; i += 512) { H1[i] = 0; H2[i] = 0; }

    const size_t bglob = (size_t)blockIdx.x * 16;
    const int u0 = wq * 8 + 2 * g;   // lane's first unit (u0, u0+1)

    // x staging: thread -> (batch sb, step-pair st2, 64B half xhalf); 64B/line per thread
    const int sb    = tid & 15;
    const int st2   = tid >> 5;
    const int xhalf = (tid >> 4) & 1;
    const float* xsrc = x + ((bglob + sb) * TSTEPS + st2) * 32 + xhalf * 16;

    float4 xv[4];
#pragma unroll
    for (int i = 0; i < 4; ++i) xv[i] = ((const float4*)xsrc)[i];

    float c[2] = {0.f, 0.f};

    for (int t0 = 0; t0 < TSTEPS; t0 += CT) {
        // ---- write prefetched x chunk to XA as split bf16, prefetch next ----
        {
            s16x8 ha, hb_, la, lb_;
#pragma unroll
            for (int k = 0; k < 4; ++k) {
                const float fv4[4] = {xv[k].x, xv[k].y, xv[k].z, xv[k].w};
#pragma unroll
                for (int j = 0; j < 4; ++j) {
                    const int idx = k * 4 + j;
                    const ushort hb = bf16rn(fv4[j]);
                    const ushort lb = bf16rn(fv4[j] - fromhi(hb));
                    if (idx < 8) { ha[idx] = (short)hb; la[idx] = (short)lb; }
                    else         { hb_[idx - 8] = (short)hb; lb_[idx - 8] = (short)lb; }
                }
            }
            const int bh = ((st2 * 2 + 0) * 16 + sb) * PITCH + xhalf * 16;
            const int bl = ((st2 * 2 + 1) * 16 + sb) * PITCH + xhalf * 16;
            *(s16x8*)&XA[bh]     = ha;
            *(s16x8*)&XA[bh + 8] = hb_;
            *(s16x8*)&XA[bl]     = la;
            *(s16x8*)&XA[bl + 8] = lb_;
        }
        if (t0 + CT < TSTEPS) {
            const float4* p = (const float4*)(xsrc + (size_t)(t0 + CT) * 32);
#pragma unroll
            for (int i = 0; i < 4; ++i) xv[i] = p[i];
        }
        __syncthreads();   // XA ready; also orders all prior-iteration LDS traffic

        if (L == 0) {
            // ---- group A: layer 1, step i = t0+tt ----
#pragma unroll
            for (int tt = 0; tt < CT; ++tt) {
                const int i = t0 + tt, rb = (i + 1) & 1, wb = i & 1;
                const s16x8 xh = *(const s16x8*)&XA[((tt * 2 + 0) * 16 + colB) * PITCH + g * 8];
                const s16x8 xl = *(const s16x8*)&XA[((tt * 2 + 1) * 16 + colB) * PITCH + g * 8];
                const s16x8 ah = *(const s16x8*)&H1[((rb * 2 + 0) * 16 + colB) * PITCH + g * 8];
                const s16x8 al = *(const s16x8*)&H1[((rb * 2 + 1) * 16 + colB) * PITCH + g * 8];
                float h[2];
                cell_pair(xh, xl, ah, al, W, c, h);
                const ushort h0 = bf16rn(h[0]), h1v = bf16rn(h[1]);
                const ushort l0 = bf16rn(h[0] - fromhi(h0)), l1 = bf16rn(h[1] - fromhi(h1v));
                *(uint*)&H1[((wb * 2 + 0) * 16 + colB) * PITCH + u0] = (uint)h0 | ((uint)h1v << 16);
                *(uint*)&H1[((wb * 2 + 1) * 16 + colB) * PITCH + u0] = (uint)l0 | ((uint)l1 << 16);
                __syncthreads();
            }
        } else {
            // ---- group B: layer 2, step i-1 ----
#pragma unroll
            for (int tt = 0; tt < CT; ++tt) {
                const int i = t0 + tt, rb = (i + 1) & 1, wb = i & 1;
                if (i > 0) {
                    const s16x8 eh = *(const s16x8*)&H1[((rb * 2 + 0) * 16 + colB) * PITCH + g * 8];
                    const s16x8 el = *(const s16x8*)&H1[((rb * 2 + 1) * 16 + colB) * PITCH + g * 8];
                    const s16x8 fh = *(const s16x8*)&H2[((wb * 2 + 0) * 16 + colB) * PITCH + g * 8];
                    const s16x8 fl = *(const s16x8*)&H2[((wb * 2 + 1) * 16 + colB) * PITCH + g * 8];
                    float h[2];
                    cell_pair(eh, el, fh, fl, W, c, h);
                    const ushort h0 = bf16rn(h[0]), h1v = bf16rn(h[1]);
                    const ushort l0 = bf16rn(h[0] - fromhi(h0)), l1 = bf16rn(h[1] - fromhi(h1v));
                    *(uint*)&H2[((rb * 2 + 0) * 16 + colB) * PITCH + u0] = (uint)h0 | ((uint)h1v << 16);
                    *(uint*)&H2[((rb * 2 + 1) * 16 + colB) * PITCH + u0] = (uint)l0 | ((uint)l1 << 16);
                }
                __syncthreads();
            }
        }
    }

    // ---- epilogue step i=512: group B computes h2[511] (reads H1[1]=h1[511], H2[0]=h2[510]) ----
    if (L == 1) {
        const s16x8 eh = *(const s16x8*)&H1[((1 * 2 + 0) * 16 + colB) * PITCH + g * 8];
        const s16x8 el = *(const s16x8*)&H1[((1 * 2 + 1) * 16 + colB) * PITCH + g * 8];
        const s16x8 fh = *(const s16x8*)&H2[((0 * 2 + 0) * 16 + colB) * PITCH + g * 8];
        const s16x8 fl = *(const s16x8*)&H2[((0 * 2 + 1) * 16 + colB) * PITCH + g * 8];
        float h[2];
        cell_pair(eh, el, fh, fl, W, c, h);
        HF[colB * 33 + u0]     = h[0];
        HF[colB * 33 + u0 + 1] = h[1];
    }
    __syncthreads();

    // ---- projection: out[b][m] ----
    if (tid < 256) {
        const int b = tid >> 4, m = tid & 15;
        float a = BPs[m];
        const float* hp = &HF[b * 33];
        const float* wp = &WPs[m * 33];
#pragma unroll
        for (int k = 0; k < 32; ++k) a = fmaf(hp[k], wp[k], a);
        out[(bglob + b) * 16 + m] = a;
    }
}

extern "C" void kernel_launch(void* const* d_in, const int* in_sizes, int n_in,
                              void* d_out, int out_size, void* d_ws, size_t ws_size,
                              hipStream_t stream) {
    const float* x     = (const float*)d_in[0];
    const float* Wih1  = (const float*)d_in[1];
    const float* Whh1  = (const float*)d_in[2];
    const float* bih1  = (const float*)d_in[3];
    const float* bhh1  = (const float*)d_in[4];
    const float* Wih2  = (const float*)d_in[5];
    const float* Whh2  = (const float*)d_in[6];
    const float* bih2  = (const float*)d_in[7];
    const float* bhh2  = (const float*)d_in[8];
    const float* Wproj = (const float*)d_in[9];
    const float* bproj = (const float*)d_in[10];
    float* out = (float*)d_out;

    dim3 grid(256), block(512);
    lstm2_pipe<<<grid, block, 0, stream>>>(x, Wih1, Whh1, bih1, bhh1,
                                           Wih2, Whh2, bih2, bhh2,
                                           Wproj, bproj, out);
}